// Round 12
// baseline (463.175 us; speedup 1.0000x reference)
//
#include <hip/hip_runtime.h>
#include <math.h>

#define NN 50000
#define NE 800000
#define KIN 256
#define F 192      // HEADS*HID
#define NH 3
#define NC 40
#define CONV_N (F*KIN + F*F + 48*F)        // 95232
#define CSR_BLKS 256
#define CHUNK 196                          // ceil(NN/CSR_BLKS)
#define EPB (NE/CSR_BLKS)                  // 3125 exactly

typedef unsigned short u16;
typedef unsigned int   u32;
typedef __attribute__((ext_vector_type(8))) short bf16x8;
typedef __attribute__((ext_vector_type(4))) float f32x4;

static __device__ __forceinline__ u16 f2bf(float f){
  u32 u = __float_as_uint(f);
  u32 r = (u + 0x7fffu + ((u >> 16) & 1u)) >> 16;   // RNE
  return (u16)r;
}

// ---------------- global barrier (all CSR_BLKS blocks co-resident: 1/CU) ----------
static __device__ __forceinline__ void gbar(int* bar, int target){
  __syncthreads();
  if (threadIdx.x == 0){
    __threadfence();                      // release: make prior stores device-visible
    atomicAdd(bar, 1);
    while (__hip_atomic_load(bar, __ATOMIC_ACQUIRE, __HIP_MEMORY_SCOPE_AGENT) < target){
      __builtin_amdgcn_s_sleep(8);
    }
  }
  __syncthreads();
  __threadfence();                        // acquire: invalidate L1 so all threads see fresh data
}

// ---------------- fused CSR build + weight converts, one launch ----------------
__global__ __launch_bounds__(256) void csr_build(
    const int* __restrict__ src, const int* __restrict__ dst,
    int* cnt, int* bar, int* partials, int* offsets, int* row_ptr, int* __restrict__ col,
    const float* __restrict__ W1, const float* __restrict__ W2, const float* __restrict__ Wout,
    u16* __restrict__ w1t, u16* __restrict__ w2t, u16* __restrict__ wot){
  const int b = blockIdx.x, t = threadIdx.x;
  const int gid = b*256 + t;
  __shared__ int ts[256];

  // P1: weight converts (independent work) + edge counting (cnt pre-zeroed by memset)
  for (int e = gid; e < CONV_N; e += CSR_BLKS*256){
    if (e < F*KIN){
      int c = e / KIN, r = e % KIN;
      w1t[e] = f2bf(W1[(size_t)r*F + c]);
    } else if (e < F*KIN + F*F){
      int e2 = e - F*KIN;
      int c = e2 / F, r = e2 % F;
      w2t[e2] = f2bf(W2[(size_t)r*F + c]);
    } else {
      int e3 = e - F*KIN - F*F;
      int n = e3 / F, k = e3 % F;
      wot[e3] = (n < NC)? f2bf(Wout[(size_t)k*NC + n]) : (u16)0;
    }
  }
  {
    const int e0 = b*EPB;
    for (int i = t; i < EPB; i += 256)
      atomicAdd(&cnt[dst[e0+i]], 1);
  }
  gbar(bar, CSR_BLKS);

  // P2: block-local inclusive scan of this block's CHUNK of cnt (kept in registers)
  const int base = b*CHUNK;
  int v = 0;
  if (t < CHUNK && base+t < NN) v = cnt[base+t];
  int incl = v;
  ts[t] = incl;
  __syncthreads();
  #pragma unroll
  for (int off=1; off<256; off<<=1){
    int u = (t>=off)? ts[t-off] : 0;
    __syncthreads();
    incl += u;
    ts[t] = incl;
    __syncthreads();
  }
  if (t == 255) partials[b] = incl;
  gbar(bar, 2*CSR_BLKS);

  // P3: block 0 scans the 256 partials -> exclusive offsets + total
  if (b == 0){
    int p = partials[t];
    int inc2 = p;
    ts[t] = inc2;
    __syncthreads();
    #pragma unroll
    for (int off=1; off<256; off<<=1){
      int u = (t>=off)? ts[t-off] : 0;
      __syncthreads();
      inc2 += u;
      ts[t] = inc2;
      __syncthreads();
    }
    offsets[t] = inc2 - p;
    if (t == 255) row_ptr[NN] = inc2;
  }
  gbar(bar, 3*CSR_BLKS);

  // P4: emit row_ptr (exclusive prefix), re-zero cnt (fill's cursor)
  if (t < CHUNK && base+t < NN){
    row_ptr[base+t] = offsets[b] + incl - v;
    cnt[base+t] = 0;
  }
  gbar(bar, 4*CSR_BLKS);

  // P5: fill
  {
    const int e0 = b*EPB;
    for (int i = t; i < EPB; i += 256){
      int d = dst[e0+i];
      int p = row_ptr[d] + atomicAdd(&cnt[d], 1);
      col[p] = src[e0+i];
    }
  }
}

// ---------------- MFMA GEMM: A[NN x K] @ Bt[192 x K](bf16) -> C[NN x 192](bf16)
// + fused attention dots. CONVA: A is fp32 (converted to bf16 during staging).
#define SAK 72   // u16 stride; dword stride 36 -> all ds ops <=2-way bank alias (free)
#define SC  196  // u16 stride for C-stage
template<int K, bool CONVA>
__global__ __launch_bounds__(256) void gemm_mfma(const void* __restrict__ Araw, const u16* __restrict__ Bt,
                                                 u16* __restrict__ C,
                                                 const float* __restrict__ att_src, const float* __restrict__ att_dst,
                                                 float* __restrict__ a_src4, float* __restrict__ a_dst4){
  __shared__ __align__(16) union {
    struct { u16 As[64*SAK]; u16 Bs[192*SAK]; } st;
    u16 Cs[64*SC];
  } sh;
  const int t = threadIdx.x;
  const int wave = t >> 6, lane = t & 63;
  const int quad = lane >> 4, l16 = lane & 15;
  const int r0 = blockIdx.x*64;

  f32x4 acc[4][3];
  #pragma unroll
  for (int rt=0;rt<4;rt++)
    #pragma unroll
    for (int ct=0;ct<3;ct++) acc[rt][ct] = (f32x4){0.f,0.f,0.f,0.f};

  for (int k0=0; k0<K; k0+=64){
    __syncthreads();
    {
      int row = t >> 2, kq = (t & 3)*16;
      bool ok = (r0+row) < NN;
      if (CONVA){
        const float* Af = (const float*)Araw;
        float4 v0 = make_float4(0,0,0,0), v1 = v0, v2 = v0, v3 = v0;
        if (ok){
          const float* p = &Af[(size_t)(r0+row)*K + k0 + kq];
          v0 = *(const float4*)(p+0);
          v1 = *(const float4*)(p+4);
          v2 = *(const float4*)(p+8);
          v3 = *(const float4*)(p+12);
        }
        uint4 pa, pb;
        pa.x = (u32)f2bf(v0.x) | ((u32)f2bf(v0.y) << 16);
        pa.y = (u32)f2bf(v0.z) | ((u32)f2bf(v0.w) << 16);
        pa.z = (u32)f2bf(v1.x) | ((u32)f2bf(v1.y) << 16);
        pa.w = (u32)f2bf(v1.z) | ((u32)f2bf(v1.w) << 16);
        pb.x = (u32)f2bf(v2.x) | ((u32)f2bf(v2.y) << 16);
        pb.y = (u32)f2bf(v2.z) | ((u32)f2bf(v2.w) << 16);
        pb.z = (u32)f2bf(v3.x) | ((u32)f2bf(v3.y) << 16);
        pb.w = (u32)f2bf(v3.z) | ((u32)f2bf(v3.w) << 16);
        *(uint4*)&sh.st.As[row*SAK + kq]     = pa;
        *(uint4*)&sh.st.As[row*SAK + kq + 8] = pb;
      } else {
        const u16* Ab = (const u16*)Araw;
        uint4 va = make_uint4(0,0,0,0), vb = va;
        if (ok){
          va = *(const uint4*)&Ab[(size_t)(r0+row)*K + k0 + kq];
          vb = *(const uint4*)&Ab[(size_t)(r0+row)*K + k0 + kq + 8];
        }
        *(uint4*)&sh.st.As[row*SAK + kq]     = va;
        *(uint4*)&sh.st.As[row*SAK + kq + 8] = vb;
      }
    }
    #pragma unroll
    for (int i=0;i<6;i++){
      int idx = t + i*256;
      int n = idx >> 3, kc = idx & 7;
      *(uint4*)&sh.st.Bs[n*SAK + kc*8] = *(const uint4*)&Bt[(size_t)n*K + k0 + kc*8];
    }
    __syncthreads();
    bf16x8 af[4][2], bf[3][2];
    #pragma unroll
    for (int kf=0;kf<2;kf++){
      #pragma unroll
      for (int rt=0;rt<4;rt++) af[rt][kf] = *(const bf16x8*)&sh.st.As[(rt*16 + l16)*SAK + kf*32 + quad*8];
      #pragma unroll
      for (int ct=0;ct<3;ct++) bf[ct][kf] = *(const bf16x8*)&sh.st.Bs[(wave*48 + ct*16 + l16)*SAK + kf*32 + quad*8];
    }
    #pragma unroll
    for (int kf=0;kf<2;kf++)
      #pragma unroll
      for (int rt=0;rt<4;rt++)
        #pragma unroll
        for (int ct=0;ct<3;ct++)
          acc[rt][ct] = __builtin_amdgcn_mfma_f32_16x16x32_bf16(af[rt][kf], bf[ct][kf], acc[rt][ct], 0, 0, 0);
  }

  __syncthreads();   // frag reads done -> safe to overwrite union with Cs
  #pragma unroll
  for (int ct=0;ct<3;ct++){
    const int n = wave*48 + ct*16 + l16;
    #pragma unroll
    for (int rt=0;rt<4;rt++){
      #pragma unroll
      for (int reg=0;reg<4;reg++){
        const int m = rt*16 + quad*4 + reg;
        sh.Cs[m*SC + n] = f2bf(acc[rt][ct][reg]);
      }
    }
  }
  __syncthreads();
  {
    int row = t >> 2, c0 = (t & 3)*6;
    int grow = r0 + row;
    if (grow < NN){
      #pragma unroll
      for (int j=0;j<6;j++){
        int ch = c0 + j;
        uint4 v = *(const uint4*)&sh.Cs[row*SC + ch*8];
        *(uint4*)&C[(size_t)grow*F + ch*8] = v;
      }
    }
  }
  if (t < 192){
    int row = t & 63, head = t >> 6;
    int grow = r0 + row;
    if (grow < NN){
      float ps = 0.f, pd = 0.f;
      #pragma unroll
      for (int j=0;j<8;j++){
        uint4 v = *(const uint4*)&sh.Cs[row*SC + head*64 + j*8];
        float4 w0 = *(const float4*)&att_src[head*64 + j*8];
        float4 w1 = *(const float4*)&att_src[head*64 + j*8 + 4];
        float4 d0 = *(const float4*)&att_dst[head*64 + j*8];
        float4 d1 = *(const float4*)&att_dst[head*64 + j*8 + 4];
        float c0f = __uint_as_float(v.x << 16), c1f = __uint_as_float(v.x & 0xffff0000u);
        float c2f = __uint_as_float(v.y << 16), c3f = __uint_as_float(v.y & 0xffff0000u);
        float c4f = __uint_as_float(v.z << 16), c5f = __uint_as_float(v.z & 0xffff0000u);
        float c6f = __uint_as_float(v.w << 16), c7f = __uint_as_float(v.w & 0xffff0000u);
        ps = fmaf(c0f,w0.x,fmaf(c1f,w0.y,fmaf(c2f,w0.z,fmaf(c3f,w0.w,ps))));
        ps = fmaf(c4f,w1.x,fmaf(c5f,w1.y,fmaf(c6f,w1.z,fmaf(c7f,w1.w,ps))));
        pd = fmaf(c0f,d0.x,fmaf(c1f,d0.y,fmaf(c2f,d0.z,fmaf(c3f,d0.w,pd))));
        pd = fmaf(c4f,d1.x,fmaf(c5f,d1.y,fmaf(c6f,d1.z,fmaf(c7f,d1.w,pd))));
      }
      a_src4[(size_t)grow*4 + head] = ps;
      a_dst4[(size_t)grow*4 + head] = pd;
    }
  }
}

// ---------------- GAT aggregation: ONE-PASS, one wave per dst node ----------------
// Unnormalized accumulate + end-folded denominators (validated R9-R11; logits bounded
// so unshifted exp is safe). Memory-latency bound; VGPR kept minimal (32) for TLP.
__global__ __launch_bounds__(256) void gat_agg_wave(const u16* __restrict__ hb,
    const float* __restrict__ a_src4, const float* __restrict__ a_dst4,
    const int* __restrict__ row_ptr, const int* __restrict__ col,
    const float* __restrict__ bias, u16* __restrict__ out){
  __shared__ float s_al[4][64][4];
  const int t = threadIdx.x;
  const int lane = t & 63;
  const int w = t >> 6;
  const int d = blockIdx.x*4 + w;
  if (d >= NN) return;
  const int e0  = row_ptr[d];
  const int deg = row_ptr[d+1] - e0;
  const int ecount = deg + 1;                 // implicit self-loop at j==deg
  const float4 ad = *(const float4*)&a_dst4[(size_t)d*4];

  const int cg = (lane < 48)? lane : lane - 48;
  const int hg = (lane < 48)? (lane >> 4) : 0;
  const int cgo = cg*4;
  float4 acc = make_float4(0.f,0.f,0.f,0.f);
  float sl0=0.f, sl1=0.f, sl2=0.f;            // per-lane denominator partials

  for (int base=0; base<ecount; base+=64){
    int j = base + lane;
    bool valid = j < ecount;
    int sn = d;
    if (j < deg) sn = col[e0+j];
    float4 as = *(const float4*)&a_src4[(size_t)sn*4];
    float l0 = as.x + ad.x; l0 = (l0>0.f)? l0 : 0.2f*l0;
    float l1 = as.y + ad.y; l1 = (l1>0.f)? l1 : 0.2f*l1;
    float l2 = as.z + ad.z; l2 = (l2>0.f)? l2 : 0.2f*l2;
    float E0 = valid? __expf(l0) : 0.f;
    float E1 = valid? __expf(l1) : 0.f;
    float E2 = valid? __expf(l2) : 0.f;
    sl0 += E0; sl1 += E1; sl2 += E2;
    float4 st; st.x = E0; st.y = E1; st.z = E2; st.w = 0.f;
    *(float4*)&s_al[w][lane][0] = st;          // coalesced ds_write_b128
    __builtin_amdgcn_wave_barrier();
    int cnt = ecount - base; if (cnt > 64) cnt = 64;
    int jj = 0;
    for (; jj+4 <= cnt; jj += 4){
      int sA = __builtin_amdgcn_readlane(sn, jj);
      int sB = __builtin_amdgcn_readlane(sn, jj+1);
      int sC = __builtin_amdgcn_readlane(sn, jj+2);
      int sD = __builtin_amdgcn_readlane(sn, jj+3);
      uint2 pA = *(const uint2*)(hb + sA*F + cgo);
      uint2 pB = *(const uint2*)(hb + sB*F + cgo);
      uint2 pC = *(const uint2*)(hb + sC*F + cgo);
      uint2 pD = *(const uint2*)(hb + sD*F + cgo);
      float aA = s_al[w][jj  ][hg];
      float aB = s_al[w][jj+1][hg];
      float aC = s_al[w][jj+2][hg];
      float aD = s_al[w][jj+3][hg];
      acc.x = fmaf(aA, __uint_as_float(pA.x << 16),         acc.x);
      acc.y = fmaf(aA, __uint_as_float(pA.x & 0xffff0000u), acc.y);
      acc.z = fmaf(aA, __uint_as_float(pA.y << 16),         acc.z);
      acc.w = fmaf(aA, __uint_as_float(pA.y & 0xffff0000u), acc.w);
      acc.x = fmaf(aB, __uint_as_float(pB.x << 16),         acc.x);
      acc.y = fmaf(aB, __uint_as_float(pB.x & 0xffff0000u), acc.y);
      acc.z = fmaf(aB, __uint_as_float(pB.y << 16),         acc.z);
      acc.w = fmaf(aB, __uint_as_float(pB.y & 0xffff0000u), acc.w);
      acc.x = fmaf(aC, __uint_as_float(pC.x << 16),         acc.x);
      acc.y = fmaf(aC, __uint_as_float(pC.x & 0xffff0000u), acc.y);
      acc.z = fmaf(aC, __uint_as_float(pC.y << 16),         acc.z);
      acc.w = fmaf(aC, __uint_as_float(pC.y & 0xffff0000u), acc.w);
      acc.x = fmaf(aD, __uint_as_float(pD.x << 16),         acc.x);
      acc.y = fmaf(aD, __uint_as_float(pD.x & 0xffff0000u), acc.y);
      acc.z = fmaf(aD, __uint_as_float(pD.y << 16),         acc.z);
      acc.w = fmaf(aD, __uint_as_float(pD.y & 0xffff0000u), acc.w);
    }
    for (; jj < cnt; jj++){
      int sA = __builtin_amdgcn_readlane(sn, jj);
      uint2 pA = *(const uint2*)(hb + sA*F + cgo);
      float aA = s_al[w][jj][hg];
      acc.x = fmaf(aA, __uint_as_float(pA.x << 16),         acc.x);
      acc.y = fmaf(aA, __uint_as_float(pA.x & 0xffff0000u), acc.y);
      acc.z = fmaf(aA, __uint_as_float(pA.y << 16),         acc.z);
      acc.w = fmaf(aA, __uint_as_float(pA.y & 0xffff0000u), acc.w);
    }
    __builtin_amdgcn_wave_barrier();
  }
  // fold denominators once
  #pragma unroll
  for (int off=32; off; off>>=1){
    sl0 += __shfl_xor(sl0, off);
    sl1 += __shfl_xor(sl1, off);
    sl2 += __shfl_xor(sl2, off);
  }
  if (lane < 48){
    float inv = 1.f / ((hg==0)? sl0 : ((hg==1)? sl1 : sl2));
    float4 b4 = *(const float4*)&bias[cg*4];
    uint2 o;
    o.x = (u32)f2bf(fmaxf(fmaf(acc.x, inv, b4.x), 0.f))
        | ((u32)f2bf(fmaxf(fmaf(acc.y, inv, b4.y), 0.f)) << 16);
    o.y = (u32)f2bf(fmaxf(fmaf(acc.z, inv, b4.z), 0.f))
        | ((u32)f2bf(fmaxf(fmaf(acc.w, inv, b4.w), 0.f)) << 16);
    *(uint2*)&out[(size_t)d*F + cg*4] = o;
  }
}

// ---------------- output GEMM via MFMA, no LDS ----------------
__global__ __launch_bounds__(256) void gemm_out_mfma(const u16* __restrict__ A,
    const u16* __restrict__ Wt, const float* __restrict__ bias, float* __restrict__ out){
  const int t = threadIdx.x;
  const int wave = t >> 6, lane = t & 63;
  const int quad = lane >> 4, l16 = lane & 15;
  const int rbase = blockIdx.x*64 + wave*16;
  const int arow = rbase + l16;
  f32x4 acc[3];
  #pragma unroll
  for (int ct=0;ct<3;ct++) acc[ct] = (f32x4){0.f,0.f,0.f,0.f};
  #pragma unroll
  for (int ks=0; ks<6; ks++){
    const int k0 = ks*32;
    union { uint4 u; bf16x8 h; } cva;
    cva.u = make_uint4(0,0,0,0);
    if (arow < NN) cva.u = *(const uint4*)&A[(size_t)arow*F + k0 + quad*8];
    #pragma unroll
    for (int ct=0;ct<3;ct++){
      bf16x8 bfr = *(const bf16x8*)&Wt[(size_t)(ct*16 + l16)*F + k0 + quad*8];
      acc[ct] = __builtin_amdgcn_mfma_f32_16x16x32_bf16(cva.h, bfr, acc[ct], 0, 0, 0);
    }
  }
  #pragma unroll
  for (int ct=0;ct<3;ct++){
    const int n = ct*16 + l16;
    #pragma unroll
    for (int reg=0;reg<4;reg++){
      const int m = quad*4 + reg;
      const int grow = rbase + m;
      if (grow < NN && n < NC) out[(size_t)grow*NC + n] = acc[ct][reg] + bias[n];
    }
  }
}

extern "C" void kernel_launch(void* const* d_in, const int* in_sizes, int n_in,
                              void* d_out, int out_size, void* d_ws, size_t ws_size,
                              hipStream_t stream){
  const float* x    = (const float*)d_in[0];
  const int*   ei   = (const int*)  d_in[1];
  const float* W1   = (const float*)d_in[2];
  const float* as1  = (const float*)d_in[3];
  const float* ad1  = (const float*)d_in[4];
  const float* b1   = (const float*)d_in[5];
  const float* W2   = (const float*)d_in[6];
  const float* as2  = (const float*)d_in[7];
  const float* ad2  = (const float*)d_in[8];
  const float* b2   = (const float*)d_in[9];
  const float* Wout = (const float*)d_in[10];
  const float* bout = (const float*)d_in[11];
  float* out = (float*)d_out;

  // workspace carve-out
  u16* w1t = (u16*)d_ws;                          // F*KIN  (W1^T bf16)
  u16* w2t = w1t + (size_t)F*KIN;                 // F*F    (W2^T bf16)
  u16* wot = w2t + (size_t)F*F;                   // 48*F   (Wout^T bf16, padded)
  u16* hb1 = wot + (size_t)48*F;                  // NN*F
  u16* hb2 = hb1 + (size_t)NN*F;                  // NN*F
  u16* gb1 = hb2 + (size_t)NN*F;                  // NN*F
  u16* gb2 = gb1 + (size_t)NN*F;                  // NN*F
  float* a_src4 = (float*)(gb2 + (size_t)NN*F);   // NN*4
  float* a_dst4 = a_src4 + (size_t)NN*4;          // NN*4
  int* row_ptr  = (int*)(a_dst4 + (size_t)NN*4);  // NN+1
  int* col      = row_ptr + (NN+1);               // NE
  int* cnt      = col + NE;                       // NN
  int* bar      = cnt + NN;                       // 1   (memset'd with cnt)
  int* partials = bar + 1;                        // CSR_BLKS
  int* offsets  = partials + CSR_BLKS;            // CSR_BLKS

  const int* srcv = ei;
  const int* dstv = ei + NE;

  // CSR build (rebuilt every call): memset zeroes cnt + bar, then ONE fused kernel
  hipMemsetAsync(cnt, 0, (NN+1)*sizeof(int), stream);
  csr_build<<<CSR_BLKS, 256, 0, stream>>>(srcv, dstv, cnt, bar, partials, offsets,
                                          row_ptr, col, W1, W2, Wout, w1t, w2t, wot);

  const int GEMM_GRID = (NN + 63)/64;
  const int AGG_GRID  = (NN + 3)/4;
  // layer 1 (x converted to bf16 inside staging)
  gemm_mfma<KIN,true><<<GEMM_GRID, 256, 0, stream>>>(x, w1t, hb1, as1, ad1, a_src4, a_dst4);
  gat_agg_wave<<<AGG_GRID, 256, 0, stream>>>(hb1, a_src4, a_dst4, row_ptr, col, b1, gb1);
  // layer 2
  gemm_mfma<F,false><<<GEMM_GRID, 256, 0, stream>>>(gb1, w2t, hb2, as2, ad2, a_src4, a_dst4);
  gat_agg_wave<<<AGG_GRID, 256, 0, stream>>>(hb2, a_src4, a_dst4, row_ptr, col, b2, gb2);
  // readout
  gemm_out_mfma<<<GEMM_GRID, 256, 0, stream>>>(gb2, wot, bout, out);
}

// Round 13
// 344.924 us; speedup vs baseline: 1.3428x; 1.3428x over previous
//
#include <hip/hip_runtime.h>
#include <math.h>

#define NN 50000
#define NE 800000
#define KIN 256
#define F 192      // HEADS*HID
#define NH 3
#define NC 40
#define NBLK 49    // ceil(NN/1024) scan blocks
#define CNT_BLKS ((NE+255)/256)            // 3125
#define CONV_N (F*KIN + F*F + 48*F)        // 95232
#define CONV_BLKS ((CONV_N+255)/256)       // 372

typedef unsigned short u16;
typedef unsigned int   u32;
typedef __attribute__((ext_vector_type(8))) short bf16x8;
typedef __attribute__((ext_vector_type(4))) float f32x4;

static __device__ __forceinline__ u16 f2bf(float f){
  u32 u = __float_as_uint(f);
  u32 r = (u + 0x7fffu + ((u >> 16) & 1u)) >> 16;   // RNE
  return (u16)r;
}

// ---------------- CSR count + (independent) weight converts, one launch ----------
// NOTE (R12 lesson): do NOT fuse the whole CSR chain with in-kernel global
// barriers — agent-scope __threadfence forces L2 writebacks (~80 MB spurious
// HBM writes, 215 µs). Kernel-boundary sync is much cheaper here.
__global__ void count_conv_kernel(const int* __restrict__ dst, int* __restrict__ cnt,
                                  const float* __restrict__ W1, const float* __restrict__ W2,
                                  const float* __restrict__ Wout,
                                  u16* __restrict__ w1t, u16* __restrict__ w2t, u16* __restrict__ wot){
  int b = blockIdx.x;
  if (b < CNT_BLKS){
    int e = b*256 + threadIdx.x;
    if (e < NE) atomicAdd(&cnt[dst[e]], 1);
    return;
  }
  int e = (b - CNT_BLKS)*256 + threadIdx.x;
  if (e < F*KIN){
    int c = e / KIN, r = e % KIN;
    w1t[e] = f2bf(W1[(size_t)r*F + c]);
    return;
  }
  int e2 = e - F*KIN;
  if (e2 < F*F){
    int c = e2 / F, r = e2 % F;
    w2t[e2] = f2bf(W2[(size_t)r*F + c]);
    return;
  }
  int e3 = e2 - F*F;
  if (e3 < 48*F){
    int n = e3 / F, k = e3 % F;
    wot[e3] = (n < NC)? f2bf(Wout[(size_t)k*NC + n]) : (u16)0;
  }
}

__global__ __launch_bounds__(256) void partial_kernel(const int* __restrict__ cnt, int* __restrict__ partials){
  __shared__ int red[256];
  const int t = threadIdx.x;
  const int base = blockIdx.x*1024 + t*4;
  int s = 0;
  if (base + 3 < NN){
    int4 v = *(const int4*)&cnt[base];
    s = v.x + v.y + v.z + v.w;
  } else if (base < NN){
    for (int i=base; i<NN; i++) s += cnt[i];
  }
  red[t] = s;
  __syncthreads();
  for (int off=128; off; off>>=1){
    if (t < off) red[t] += red[t+off];
    __syncthreads();
  }
  if (t==0) partials[blockIdx.x] = red[0];
}

__global__ __launch_bounds__(64) void scan_partials(const int* __restrict__ partials,
                                                    int* __restrict__ offsets, int* __restrict__ row_ptr){
  const int lane = threadIdx.x;
  int p = (lane < NBLK)? partials[lane] : 0;
  int inc = p;
  #pragma unroll
  for (int off=1; off<64; off<<=1){
    int v = __shfl_up(inc, off);
    if (lane >= off) inc += v;
  }
  if (lane < NBLK) offsets[lane] = inc - p;
  if (lane == NBLK-1) row_ptr[NN] = inc;
}

// emit row_ptr AND zero cnt (fill reuses cnt as cursor)
__global__ __launch_bounds__(256) void emit_kernel(int* __restrict__ cnt,
                                                   const int* __restrict__ offsets,
                                                   int* __restrict__ row_ptr){
  __shared__ int ts[256];
  const int t = threadIdx.x;
  const int base = blockIdx.x*1024 + t*4;
  int4 v = make_int4(0,0,0,0);
  if (base + 3 < NN) v = *(const int4*)&cnt[base];
  else if (base < NN){
    v.x = cnt[base];
    if (base+1 < NN) v.y = cnt[base+1];
    if (base+2 < NN) v.z = cnt[base+2];
  }
  int tot = v.x + v.y + v.z + v.w;
  ts[t] = tot;
  __syncthreads();
  #pragma unroll
  for (int off=1; off<256; off<<=1){
    int val = (t >= off)? ts[t-off] : 0;
    __syncthreads();
    ts[t] += val;
    __syncthreads();
  }
  int off0 = offsets[blockIdx.x] + ts[t] - tot;
  if (base + 3 < NN){
    row_ptr[base]   = off0;
    row_ptr[base+1] = off0 + v.x;
    row_ptr[base+2] = off0 + v.x + v.y;
    row_ptr[base+3] = off0 + v.x + v.y + v.z;
    *(int4*)&cnt[base] = make_int4(0,0,0,0);
  } else if (base < NN){
    row_ptr[base] = off0; cnt[base] = 0;
    if (base+1 < NN){ row_ptr[base+1] = off0 + v.x; cnt[base+1] = 0; }
    if (base+2 < NN){ row_ptr[base+2] = off0 + v.x + v.y; cnt[base+2] = 0; }
  }
}

__global__ void fill_kernel(const int* __restrict__ src, const int* __restrict__ dst,
                            const int* __restrict__ row_ptr, int* __restrict__ cur,
                            int* __restrict__ col){
  int e = blockIdx.x*256 + threadIdx.x;
  if (e < NE){
    int d = dst[e];
    int p = row_ptr[d] + atomicAdd(&cur[d], 1);
    col[p] = src[e];
  }
}

// ---------------- MFMA GEMM: A[NN x K] @ Bt[192 x K](bf16) -> C[NN x 192](bf16)
// + fused attention dots. CONVA: A is fp32 (converted to bf16 during staging).
#define SAK 72   // u16 stride; dword stride 36 -> all ds ops <=2-way bank alias (free)
#define SC  196  // u16 stride for C-stage
template<int K, bool CONVA>
__global__ __launch_bounds__(256) void gemm_mfma(const void* __restrict__ Araw, const u16* __restrict__ Bt,
                                                 u16* __restrict__ C,
                                                 const float* __restrict__ att_src, const float* __restrict__ att_dst,
                                                 float* __restrict__ a_src4, float* __restrict__ a_dst4){
  __shared__ __align__(16) union {
    struct { u16 As[64*SAK]; u16 Bs[192*SAK]; } st;
    u16 Cs[64*SC];
  } sh;
  const int t = threadIdx.x;
  const int wave = t >> 6, lane = t & 63;
  const int quad = lane >> 4, l16 = lane & 15;
  const int r0 = blockIdx.x*64;

  f32x4 acc[4][3];
  #pragma unroll
  for (int rt=0;rt<4;rt++)
    #pragma unroll
    for (int ct=0;ct<3;ct++) acc[rt][ct] = (f32x4){0.f,0.f,0.f,0.f};

  for (int k0=0; k0<K; k0+=64){
    __syncthreads();
    {
      int row = t >> 2, kq = (t & 3)*16;
      bool ok = (r0+row) < NN;
      if (CONVA){
        const float* Af = (const float*)Araw;
        float4 v0 = make_float4(0,0,0,0), v1 = v0, v2 = v0, v3 = v0;
        if (ok){
          const float* p = &Af[(size_t)(r0+row)*K + k0 + kq];
          v0 = *(const float4*)(p+0);
          v1 = *(const float4*)(p+4);
          v2 = *(const float4*)(p+8);
          v3 = *(const float4*)(p+12);
        }
        uint4 pa, pb;
        pa.x = (u32)f2bf(v0.x) | ((u32)f2bf(v0.y) << 16);
        pa.y = (u32)f2bf(v0.z) | ((u32)f2bf(v0.w) << 16);
        pa.z = (u32)f2bf(v1.x) | ((u32)f2bf(v1.y) << 16);
        pa.w = (u32)f2bf(v1.z) | ((u32)f2bf(v1.w) << 16);
        pb.x = (u32)f2bf(v2.x) | ((u32)f2bf(v2.y) << 16);
        pb.y = (u32)f2bf(v2.z) | ((u32)f2bf(v2.w) << 16);
        pb.z = (u32)f2bf(v3.x) | ((u32)f2bf(v3.y) << 16);
        pb.w = (u32)f2bf(v3.z) | ((u32)f2bf(v3.w) << 16);
        *(uint4*)&sh.st.As[row*SAK + kq]     = pa;
        *(uint4*)&sh.st.As[row*SAK + kq + 8] = pb;
      } else {
        const u16* Ab = (const u16*)Araw;
        uint4 va = make_uint4(0,0,0,0), vb = va;
        if (ok){
          va = *(const uint4*)&Ab[(size_t)(r0+row)*K + k0 + kq];
          vb = *(const uint4*)&Ab[(size_t)(r0+row)*K + k0 + kq + 8];
        }
        *(uint4*)&sh.st.As[row*SAK + kq]     = va;
        *(uint4*)&sh.st.As[row*SAK + kq + 8] = vb;
      }
    }
    #pragma unroll
    for (int i=0;i<6;i++){
      int idx = t + i*256;
      int n = idx >> 3, kc = idx & 7;
      *(uint4*)&sh.st.Bs[n*SAK + kc*8] = *(const uint4*)&Bt[(size_t)n*K + k0 + kc*8];
    }
    __syncthreads();
    bf16x8 af[4][2], bf[3][2];
    #pragma unroll
    for (int kf=0;kf<2;kf++){
      #pragma unroll
      for (int rt=0;rt<4;rt++) af[rt][kf] = *(const bf16x8*)&sh.st.As[(rt*16 + l16)*SAK + kf*32 + quad*8];
      #pragma unroll
      for (int ct=0;ct<3;ct++) bf[ct][kf] = *(const bf16x8*)&sh.st.Bs[(wave*48 + ct*16 + l16)*SAK + kf*32 + quad*8];
    }
    #pragma unroll
    for (int kf=0;kf<2;kf++)
      #pragma unroll
      for (int rt=0;rt<4;rt++)
        #pragma unroll
        for (int ct=0;ct<3;ct++)
          acc[rt][ct] = __builtin_amdgcn_mfma_f32_16x16x32_bf16(af[rt][kf], bf[ct][kf], acc[rt][ct], 0, 0, 0);
  }

  __syncthreads();   // frag reads done -> safe to overwrite union with Cs
  #pragma unroll
  for (int ct=0;ct<3;ct++){
    const int n = wave*48 + ct*16 + l16;
    #pragma unroll
    for (int rt=0;rt<4;rt++){
      #pragma unroll
      for (int reg=0;reg<4;reg++){
        const int m = rt*16 + quad*4 + reg;
        sh.Cs[m*SC + n] = f2bf(acc[rt][ct][reg]);
      }
    }
  }
  __syncthreads();
  {
    int row = t >> 2, c0 = (t & 3)*6;
    int grow = r0 + row;
    if (grow < NN){
      #pragma unroll
      for (int j=0;j<6;j++){
        int ch = c0 + j;
        uint4 v = *(const uint4*)&sh.Cs[row*SC + ch*8];
        *(uint4*)&C[(size_t)grow*F + ch*8] = v;
      }
    }
  }
  if (t < 192){
    int row = t & 63, head = t >> 6;
    int grow = r0 + row;
    if (grow < NN){
      float ps = 0.f, pd = 0.f;
      #pragma unroll
      for (int j=0;j<8;j++){
        uint4 v = *(const uint4*)&sh.Cs[row*SC + head*64 + j*8];
        float4 w0 = *(const float4*)&att_src[head*64 + j*8];
        float4 w1 = *(const float4*)&att_src[head*64 + j*8 + 4];
        float4 d0 = *(const float4*)&att_dst[head*64 + j*8];
        float4 d1 = *(const float4*)&att_dst[head*64 + j*8 + 4];
        float c0f = __uint_as_float(v.x << 16), c1f = __uint_as_float(v.x & 0xffff0000u);
        float c2f = __uint_as_float(v.y << 16), c3f = __uint_as_float(v.y & 0xffff0000u);
        float c4f = __uint_as_float(v.z << 16), c5f = __uint_as_float(v.z & 0xffff0000u);
        float c6f = __uint_as_float(v.w << 16), c7f = __uint_as_float(v.w & 0xffff0000u);
        ps = fmaf(c0f,w0.x,fmaf(c1f,w0.y,fmaf(c2f,w0.z,fmaf(c3f,w0.w,ps))));
        ps = fmaf(c4f,w1.x,fmaf(c5f,w1.y,fmaf(c6f,w1.z,fmaf(c7f,w1.w,ps))));
        pd = fmaf(c0f,d0.x,fmaf(c1f,d0.y,fmaf(c2f,d0.z,fmaf(c3f,d0.w,pd))));
        pd = fmaf(c4f,d1.x,fmaf(c5f,d1.y,fmaf(c6f,d1.z,fmaf(c7f,d1.w,pd))));
      }
      a_src4[(size_t)grow*4 + head] = ps;
      a_dst4[(size_t)grow*4 + head] = pd;
    }
  }
}

// ---------------- GAT aggregation: ONE-PASS, one wave per dst node ----------------
// Unnormalized accumulate + end-folded denominators (validated R9-R11; logits bounded
// so unshifted exp is safe). Memory-latency bound; VGPR kept minimal for TLP.
__global__ __launch_bounds__(256) void gat_agg_wave(const u16* __restrict__ hb,
    const float* __restrict__ a_src4, const float* __restrict__ a_dst4,
    const int* __restrict__ row_ptr, const int* __restrict__ col,
    const float* __restrict__ bias, u16* __restrict__ out){
  __shared__ float s_al[4][64][4];
  const int t = threadIdx.x;
  const int lane = t & 63;
  const int w = t >> 6;
  const int d = blockIdx.x*4 + w;
  if (d >= NN) return;
  const int e0  = row_ptr[d];
  const int deg = row_ptr[d+1] - e0;
  const int ecount = deg + 1;                 // implicit self-loop at j==deg
  const float4 ad = *(const float4*)&a_dst4[(size_t)d*4];

  const int cg = (lane < 48)? lane : lane - 48;
  const int hg = (lane < 48)? (lane >> 4) : 0;
  const int cgo = cg*4;
  float4 acc = make_float4(0.f,0.f,0.f,0.f);
  float sl0=0.f, sl1=0.f, sl2=0.f;            // per-lane denominator partials

  for (int base=0; base<ecount; base+=64){
    int j = base + lane;
    bool valid = j < ecount;
    int sn = d;
    if (j < deg) sn = col[e0+j];
    float4 as = *(const float4*)&a_src4[(size_t)sn*4];
    float l0 = as.x + ad.x; l0 = (l0>0.f)? l0 : 0.2f*l0;
    float l1 = as.y + ad.y; l1 = (l1>0.f)? l1 : 0.2f*l1;
    float l2 = as.z + ad.z; l2 = (l2>0.f)? l2 : 0.2f*l2;
    float E0 = valid? __expf(l0) : 0.f;
    float E1 = valid? __expf(l1) : 0.f;
    float E2 = valid? __expf(l2) : 0.f;
    sl0 += E0; sl1 += E1; sl2 += E2;
    float4 st; st.x = E0; st.y = E1; st.z = E2; st.w = 0.f;
    *(float4*)&s_al[w][lane][0] = st;          // coalesced ds_write_b128
    __builtin_amdgcn_wave_barrier();
    int cnt = ecount - base; if (cnt > 64) cnt = 64;
    int jj = 0;
    for (; jj+4 <= cnt; jj += 4){
      int sA = __builtin_amdgcn_readlane(sn, jj);
      int sB = __builtin_amdgcn_readlane(sn, jj+1);
      int sC = __builtin_amdgcn_readlane(sn, jj+2);
      int sD = __builtin_amdgcn_readlane(sn, jj+3);
      uint2 pA = *(const uint2*)(hb + sA*F + cgo);
      uint2 pB = *(const uint2*)(hb + sB*F + cgo);
      uint2 pC = *(const uint2*)(hb + sC*F + cgo);
      uint2 pD = *(const uint2*)(hb + sD*F + cgo);
      float aA = s_al[w][jj  ][hg];
      float aB = s_al[w][jj+1][hg];
      float aC = s_al[w][jj+2][hg];
      float aD = s_al[w][jj+3][hg];
      acc.x = fmaf(aA, __uint_as_float(pA.x << 16),         acc.x);
      acc.y = fmaf(aA, __uint_as_float(pA.x & 0xffff0000u), acc.y);
      acc.z = fmaf(aA, __uint_as_float(pA.y << 16),         acc.z);
      acc.w = fmaf(aA, __uint_as_float(pA.y & 0xffff0000u), acc.w);
      acc.x = fmaf(aB, __uint_as_float(pB.x << 16),         acc.x);
      acc.y = fmaf(aB, __uint_as_float(pB.x & 0xffff0000u), acc.y);
      acc.z = fmaf(aB, __uint_as_float(pB.y << 16),         acc.z);
      acc.w = fmaf(aB, __uint_as_float(pB.y & 0xffff0000u), acc.w);
      acc.x = fmaf(aC, __uint_as_float(pC.x << 16),         acc.x);
      acc.y = fmaf(aC, __uint_as_float(pC.x & 0xffff0000u), acc.y);
      acc.z = fmaf(aC, __uint_as_float(pC.y << 16),         acc.z);
      acc.w = fmaf(aC, __uint_as_float(pC.y & 0xffff0000u), acc.w);
      acc.x = fmaf(aD, __uint_as_float(pD.x << 16),         acc.x);
      acc.y = fmaf(aD, __uint_as_float(pD.x & 0xffff0000u), acc.y);
      acc.z = fmaf(aD, __uint_as_float(pD.y << 16),         acc.z);
      acc.w = fmaf(aD, __uint_as_float(pD.y & 0xffff0000u), acc.w);
    }
    for (; jj < cnt; jj++){
      int sA = __builtin_amdgcn_readlane(sn, jj);
      uint2 pA = *(const uint2*)(hb + sA*F + cgo);
      float aA = s_al[w][jj][hg];
      acc.x = fmaf(aA, __uint_as_float(pA.x << 16),         acc.x);
      acc.y = fmaf(aA, __uint_as_float(pA.x & 0xffff0000u), acc.y);
      acc.z = fmaf(aA, __uint_as_float(pA.y << 16),         acc.z);
      acc.w = fmaf(aA, __uint_as_float(pA.y & 0xffff0000u), acc.w);
    }
    __builtin_amdgcn_wave_barrier();
  }
  // fold denominators once
  #pragma unroll
  for (int off=32; off; off>>=1){
    sl0 += __shfl_xor(sl0, off);
    sl1 += __shfl_xor(sl1, off);
    sl2 += __shfl_xor(sl2, off);
  }
  if (lane < 48){
    float inv = 1.f / ((hg==0)? sl0 : ((hg==1)? sl1 : sl2));
    float4 b4 = *(const float4*)&bias[cg*4];
    uint2 o;
    o.x = (u32)f2bf(fmaxf(fmaf(acc.x, inv, b4.x), 0.f))
        | ((u32)f2bf(fmaxf(fmaf(acc.y, inv, b4.y), 0.f)) << 16);
    o.y = (u32)f2bf(fmaxf(fmaf(acc.z, inv, b4.z), 0.f))
        | ((u32)f2bf(fmaxf(fmaf(acc.w, inv, b4.w), 0.f)) << 16);
    *(uint2*)&out[(size_t)d*F + cg*4] = o;
  }
}

// ---------------- output GEMM via MFMA, no LDS ----------------
__global__ __launch_bounds__(256) void gemm_out_mfma(const u16* __restrict__ A,
    const u16* __restrict__ Wt, const float* __restrict__ bias, float* __restrict__ out){
  const int t = threadIdx.x;
  const int wave = t >> 6, lane = t & 63;
  const int quad = lane >> 4, l16 = lane & 15;
  const int rbase = blockIdx.x*64 + wave*16;
  const int arow = rbase + l16;
  f32x4 acc[3];
  #pragma unroll
  for (int ct=0;ct<3;ct++) acc[ct] = (f32x4){0.f,0.f,0.f,0.f};
  #pragma unroll
  for (int ks=0; ks<6; ks++){
    const int k0 = ks*32;
    union { uint4 u; bf16x8 h; } cva;
    cva.u = make_uint4(0,0,0,0);
    if (arow < NN) cva.u = *(const uint4*)&A[(size_t)arow*F + k0 + quad*8];
    #pragma unroll
    for (int ct=0;ct<3;ct++){
      bf16x8 bfr = *(const bf16x8*)&Wt[(size_t)(ct*16 + l16)*F + k0 + quad*8];
      acc[ct] = __builtin_amdgcn_mfma_f32_16x16x32_bf16(cva.h, bfr, acc[ct], 0, 0, 0);
    }
  }
  #pragma unroll
  for (int ct=0;ct<3;ct++){
    const int n = ct*16 + l16;
    #pragma unroll
    for (int reg=0;reg<4;reg++){
      const int m = quad*4 + reg;
      const int grow = rbase + m;
      if (grow < NN && n < NC) out[(size_t)grow*NC + n] = acc[ct][reg] + bias[n];
    }
  }
}

extern "C" void kernel_launch(void* const* d_in, const int* in_sizes, int n_in,
                              void* d_out, int out_size, void* d_ws, size_t ws_size,
                              hipStream_t stream){
  const float* x    = (const float*)d_in[0];
  const int*   ei   = (const int*)  d_in[1];
  const float* W1   = (const float*)d_in[2];
  const float* as1  = (const float*)d_in[3];
  const float* ad1  = (const float*)d_in[4];
  const float* b1   = (const float*)d_in[5];
  const float* W2   = (const float*)d_in[6];
  const float* as2  = (const float*)d_in[7];
  const float* ad2  = (const float*)d_in[8];
  const float* b2   = (const float*)d_in[9];
  const float* Wout = (const float*)d_in[10];
  const float* bout = (const float*)d_in[11];
  float* out = (float*)d_out;

  // workspace carve-out
  u16* w1t = (u16*)d_ws;                          // F*KIN  (W1^T bf16)
  u16* w2t = w1t + (size_t)F*KIN;                 // F*F    (W2^T bf16)
  u16* wot = w2t + (size_t)F*F;                   // 48*F   (Wout^T bf16, padded)
  u16* hb1 = wot + (size_t)48*F;                  // NN*F
  u16* hb2 = hb1 + (size_t)NN*F;                  // NN*F
  u16* gb1 = hb2 + (size_t)NN*F;                  // NN*F
  u16* gb2 = gb1 + (size_t)NN*F;                  // NN*F
  float* a_src4 = (float*)(gb2 + (size_t)NN*F);   // NN*4
  float* a_dst4 = a_src4 + (size_t)NN*4;          // NN*4
  int* row_ptr  = (int*)(a_dst4 + (size_t)NN*4);  // NN+1
  int* col      = row_ptr + (NN+1);               // NE
  int* cnt      = col + NE;                       // NN
  int* partials = cnt + NN;                       // NBLK
  int* offsets  = partials + NBLK;                // NBLK

  const int* srcv = ei;
  const int* dstv = ei + NE;

  // CSR by destination (rebuilt every call) + weight converts fused into count
  hipMemsetAsync(cnt, 0, NN*sizeof(int), stream);
  count_conv_kernel<<<CNT_BLKS + CONV_BLKS, 256, 0, stream>>>(dstv, cnt, W1, W2, Wout, w1t, w2t, wot);
  partial_kernel<<<NBLK, 256, 0, stream>>>(cnt, partials);
  scan_partials<<<1, 64, 0, stream>>>(partials, offsets, row_ptr);
  emit_kernel<<<NBLK, 256, 0, stream>>>(cnt, offsets, row_ptr);
  fill_kernel<<<(NE+255)/256, 256, 0, stream>>>(srcv, dstv, row_ptr, cnt, col);

  const int GEMM_GRID = (NN + 63)/64;
  const int AGG_GRID  = (NN + 3)/4;
  // layer 1 (x converted to bf16 inside staging)
  gemm_mfma<KIN,true><<<GEMM_GRID, 256, 0, stream>>>(x, w1t, hb1, as1, ad1, a_src4, a_dst4);
  gat_agg_wave<<<AGG_GRID, 256, 0, stream>>>(hb1, a_src4, a_dst4, row_ptr, col, b1, gb1);
  // layer 2
  gemm_mfma<F,false><<<GEMM_GRID, 256, 0, stream>>>(gb1, w2t, hb2, as2, ad2, a_src4, a_dst4);
  gat_agg_wave<<<AGG_GRID, 256, 0, stream>>>(hb2, a_src4, a_dst4, row_ptr, col, b2, gb2);
  // readout
  gemm_out_mfma<<<GEMM_GRID, 256, 0, stream>>>(gb2, wot, bout, out);
}

// Round 14
// 338.547 us; speedup vs baseline: 1.3681x; 1.0188x over previous
//
#include <hip/hip_runtime.h>
#include <math.h>

#define NN 50000
#define NE 800000
#define KIN 256
#define F 192      // HEADS*HID
#define NH 3
#define NC 40
#define CNT_BLKS ((NE+255)/256)            // 3125
#define CONV_N (F*KIN + F*F + 48*F)        // 95232
#define CONV_BLKS ((CONV_N+255)/256)       // 372
#define GEMM_GRID_C ((NN+63)/64)           // 782
#define EMIT_BLKS 49                       // ceil(NN/1024)

typedef unsigned short u16;
typedef unsigned int   u32;
typedef __attribute__((ext_vector_type(8))) short bf16x8;
typedef __attribute__((ext_vector_type(4))) float f32x4;

static __device__ __forceinline__ u16 f2bf(float f){
  u32 u = __float_as_uint(f);
  u32 r = (u + 0x7fffu + ((u >> 16) & 1u)) >> 16;   // RNE
  return (u16)r;
}

// ---------------- CSR count + (independent) weight converts, one launch ----------
// R12 lesson: no in-kernel agent fences (L2 writeback storm). Fusion only at
// dispatch granularity with disjoint block ranges.
__global__ void count_conv_kernel(const int* __restrict__ dst, int* __restrict__ cnt,
                                  const float* __restrict__ W1, const float* __restrict__ W2,
                                  const float* __restrict__ Wout,
                                  u16* __restrict__ w1t, u16* __restrict__ w2t, u16* __restrict__ wot){
  int b = blockIdx.x;
  if (b < CNT_BLKS){
    int e = b*256 + threadIdx.x;
    if (e < NE) atomicAdd(&cnt[dst[e]], 1);
    return;
  }
  int e = (b - CNT_BLKS)*256 + threadIdx.x;
  if (e < F*KIN){
    int c = e / KIN, r = e % KIN;
    w1t[e] = f2bf(W1[(size_t)r*F + c]);
    return;
  }
  int e2 = e - F*KIN;
  if (e2 < F*F){
    int c = e2 / F, r = e2 % F;
    w2t[e2] = f2bf(W2[(size_t)r*F + c]);
    return;
  }
  int e3 = e2 - F*F;
  if (e3 < 48*F){
    int n = e3 / F, k = e3 % F;
    wot[e3] = (n < NC)? f2bf(Wout[(size_t)k*NC + n]) : (u16)0;
  }
}

// ---------------- fused partial+scan+emit: each block redundantly computes its
// predecessor sum (<=48K ints from L2, ~1 us), scans its own 1024-chunk, emits
// row_ptr, zeroes cnt (fill's cursor). row_ptr[NN] == NE (constant).
__global__ __launch_bounds__(256) void emit_all(int* __restrict__ cnt, int* __restrict__ row_ptr){
  __shared__ int ts[256];
  __shared__ int s_pred;
  const int b = blockIdx.x, t = threadIdx.x;
  const int lim = b*1024;
  // predecessor sum
  int pred = 0;
  for (int i = t*4; i < lim; i += 1024){
    int4 v = *(const int4*)&cnt[i];
    pred += v.x + v.y + v.z + v.w;
  }
  ts[t] = pred;
  __syncthreads();
  for (int off=128; off; off>>=1){
    if (t < off) ts[t] += ts[t+off];
    __syncthreads();
  }
  if (t == 0) s_pred = ts[0];
  __syncthreads();
  // own chunk
  const int base = lim + t*4;
  int4 v = make_int4(0,0,0,0);
  if (base + 3 < NN) v = *(const int4*)&cnt[base];
  else if (base < NN){
    v.x = cnt[base];
    if (base+1 < NN) v.y = cnt[base+1];
    if (base+2 < NN) v.z = cnt[base+2];
  }
  int tot = v.x + v.y + v.z + v.w;
  ts[t] = tot;
  __syncthreads();
  #pragma unroll
  for (int off=1; off<256; off<<=1){
    int val = (t >= off)? ts[t-off] : 0;
    __syncthreads();
    ts[t] += val;
    __syncthreads();
  }
  int off0 = s_pred + ts[t] - tot;   // exclusive prefix
  if (base + 3 < NN){
    row_ptr[base]   = off0;
    row_ptr[base+1] = off0 + v.x;
    row_ptr[base+2] = off0 + v.x + v.y;
    row_ptr[base+3] = off0 + v.x + v.y + v.z;
    *(int4*)&cnt[base] = make_int4(0,0,0,0);
  } else if (base < NN){
    row_ptr[base] = off0; cnt[base] = 0;
    if (base+1 < NN){ row_ptr[base+1] = off0 + v.x; cnt[base+1] = 0; }
    if (base+2 < NN){ row_ptr[base+2] = off0 + v.x + v.y; cnt[base+2] = 0; }
  }
  if (b == 0 && t == 0) row_ptr[NN] = NE;
}

// ---------------- MFMA GEMM: A[NN x K] @ Bt[192 x K](bf16) -> C[NN x 192](bf16)
// + fused attention dots. CONVA: A fp32 converted during staging. FILL: blocks
// beyond GEMM_GRID_C do the CSR fill (independent work, overlaps with MFMA).
#define SAK 72   // u16 stride; dword stride 36 -> all ds ops <=2-way bank alias (free)
#define SC  196  // u16 stride for C-stage
template<int K, bool CONVA, bool FILL>
__global__ __launch_bounds__(256) void gemm_mfma(const void* __restrict__ Araw, const u16* __restrict__ Bt,
                                                 u16* __restrict__ C,
                                                 const float* __restrict__ att_src, const float* __restrict__ att_dst,
                                                 float* __restrict__ a_src4, float* __restrict__ a_dst4,
                                                 const int* __restrict__ fsrc, const int* __restrict__ fdst,
                                                 const int* __restrict__ row_ptr, int* __restrict__ cur,
                                                 int* __restrict__ col){
  if (FILL && blockIdx.x >= GEMM_GRID_C){
    int e = (blockIdx.x - GEMM_GRID_C)*256 + threadIdx.x;
    if (e < NE){
      int d = fdst[e];
      int p = row_ptr[d] + atomicAdd(&cur[d], 1);
      col[p] = fsrc[e];
    }
    return;
  }
  __shared__ __align__(16) union {
    struct { u16 As[64*SAK]; u16 Bs[192*SAK]; } st;
    u16 Cs[64*SC];
  } sh;
  const int t = threadIdx.x;
  const int wave = t >> 6, lane = t & 63;
  const int quad = lane >> 4, l16 = lane & 15;
  const int r0 = blockIdx.x*64;

  f32x4 acc[4][3];
  #pragma unroll
  for (int rt=0;rt<4;rt++)
    #pragma unroll
    for (int ct=0;ct<3;ct++) acc[rt][ct] = (f32x4){0.f,0.f,0.f,0.f};

  for (int k0=0; k0<K; k0+=64){
    __syncthreads();
    {
      int row = t >> 2, kq = (t & 3)*16;
      bool ok = (r0+row) < NN;
      if (CONVA){
        const float* Af = (const float*)Araw;
        float4 v0 = make_float4(0,0,0,0), v1 = v0, v2 = v0, v3 = v0;
        if (ok){
          const float* p = &Af[(size_t)(r0+row)*K + k0 + kq];
          v0 = *(const float4*)(p+0);
          v1 = *(const float4*)(p+4);
          v2 = *(const float4*)(p+8);
          v3 = *(const float4*)(p+12);
        }
        uint4 pa, pb;
        pa.x = (u32)f2bf(v0.x) | ((u32)f2bf(v0.y) << 16);
        pa.y = (u32)f2bf(v0.z) | ((u32)f2bf(v0.w) << 16);
        pa.z = (u32)f2bf(v1.x) | ((u32)f2bf(v1.y) << 16);
        pa.w = (u32)f2bf(v1.z) | ((u32)f2bf(v1.w) << 16);
        pb.x = (u32)f2bf(v2.x) | ((u32)f2bf(v2.y) << 16);
        pb.y = (u32)f2bf(v2.z) | ((u32)f2bf(v2.w) << 16);
        pb.z = (u32)f2bf(v3.x) | ((u32)f2bf(v3.y) << 16);
        pb.w = (u32)f2bf(v3.z) | ((u32)f2bf(v3.w) << 16);
        *(uint4*)&sh.st.As[row*SAK + kq]     = pa;
        *(uint4*)&sh.st.As[row*SAK + kq + 8] = pb;
      } else {
        const u16* Ab = (const u16*)Araw;
        uint4 va = make_uint4(0,0,0,0), vb = va;
        if (ok){
          va = *(const uint4*)&Ab[(size_t)(r0+row)*K + k0 + kq];
          vb = *(const uint4*)&Ab[(size_t)(r0+row)*K + k0 + kq + 8];
        }
        *(uint4*)&sh.st.As[row*SAK + kq]     = va;
        *(uint4*)&sh.st.As[row*SAK + kq + 8] = vb;
      }
    }
    #pragma unroll
    for (int i=0;i<6;i++){
      int idx = t + i*256;
      int n = idx >> 3, kc = idx & 7;
      *(uint4*)&sh.st.Bs[n*SAK + kc*8] = *(const uint4*)&Bt[(size_t)n*K + k0 + kc*8];
    }
    __syncthreads();
    bf16x8 af[4][2], bf[3][2];
    #pragma unroll
    for (int kf=0;kf<2;kf++){
      #pragma unroll
      for (int rt=0;rt<4;rt++) af[rt][kf] = *(const bf16x8*)&sh.st.As[(rt*16 + l16)*SAK + kf*32 + quad*8];
      #pragma unroll
      for (int ct=0;ct<3;ct++) bf[ct][kf] = *(const bf16x8*)&sh.st.Bs[(wave*48 + ct*16 + l16)*SAK + kf*32 + quad*8];
    }
    #pragma unroll
    for (int kf=0;kf<2;kf++)
      #pragma unroll
      for (int rt=0;rt<4;rt++)
        #pragma unroll
        for (int ct=0;ct<3;ct++)
          acc[rt][ct] = __builtin_amdgcn_mfma_f32_16x16x32_bf16(af[rt][kf], bf[ct][kf], acc[rt][ct], 0, 0, 0);
  }

  __syncthreads();   // frag reads done -> safe to overwrite union with Cs
  #pragma unroll
  for (int ct=0;ct<3;ct++){
    const int n = wave*48 + ct*16 + l16;
    #pragma unroll
    for (int rt=0;rt<4;rt++){
      #pragma unroll
      for (int reg=0;reg<4;reg++){
        const int m = rt*16 + quad*4 + reg;
        sh.Cs[m*SC + n] = f2bf(acc[rt][ct][reg]);
      }
    }
  }
  __syncthreads();
  {
    int row = t >> 2, c0 = (t & 3)*6;
    int grow = r0 + row;
    if (grow < NN){
      #pragma unroll
      for (int j=0;j<6;j++){
        int ch = c0 + j;
        uint4 v = *(const uint4*)&sh.Cs[row*SC + ch*8];
        *(uint4*)&C[(size_t)grow*F + ch*8] = v;
      }
    }
  }
  if (t < 192){
    int row = t & 63, head = t >> 6;
    int grow = r0 + row;
    if (grow < NN){
      float ps = 0.f, pd = 0.f;
      #pragma unroll
      for (int j=0;j<8;j++){
        uint4 v = *(const uint4*)&sh.Cs[row*SC + head*64 + j*8];
        float4 w0 = *(const float4*)&att_src[head*64 + j*8];
        float4 w1 = *(const float4*)&att_src[head*64 + j*8 + 4];
        float4 d0 = *(const float4*)&att_dst[head*64 + j*8];
        float4 d1 = *(const float4*)&att_dst[head*64 + j*8 + 4];
        float c0f = __uint_as_float(v.x << 16), c1f = __uint_as_float(v.x & 0xffff0000u);
        float c2f = __uint_as_float(v.y << 16), c3f = __uint_as_float(v.y & 0xffff0000u);
        float c4f = __uint_as_float(v.z << 16), c5f = __uint_as_float(v.z & 0xffff0000u);
        float c6f = __uint_as_float(v.w << 16), c7f = __uint_as_float(v.w & 0xffff0000u);
        ps = fmaf(c0f,w0.x,fmaf(c1f,w0.y,fmaf(c2f,w0.z,fmaf(c3f,w0.w,ps))));
        ps = fmaf(c4f,w1.x,fmaf(c5f,w1.y,fmaf(c6f,w1.z,fmaf(c7f,w1.w,ps))));
        pd = fmaf(c0f,d0.x,fmaf(c1f,d0.y,fmaf(c2f,d0.z,fmaf(c3f,d0.w,pd))));
        pd = fmaf(c4f,d1.x,fmaf(c5f,d1.y,fmaf(c6f,d1.z,fmaf(c7f,d1.w,pd))));
      }
      a_src4[(size_t)grow*4 + head] = ps;
      a_dst4[(size_t)grow*4 + head] = pd;
    }
  }
}

// ---------------- GAT aggregation: ONE-PASS, one wave per dst node ----------------
__global__ __launch_bounds__(256) void gat_agg_wave(const u16* __restrict__ hb,
    const float* __restrict__ a_src4, const float* __restrict__ a_dst4,
    const int* __restrict__ row_ptr, const int* __restrict__ col,
    const float* __restrict__ bias, u16* __restrict__ out){
  __shared__ float s_al[4][64][4];
  const int t = threadIdx.x;
  const int lane = t & 63;
  const int w = t >> 6;
  const int d = blockIdx.x*4 + w;
  if (d >= NN) return;
  const int e0  = row_ptr[d];
  const int deg = row_ptr[d+1] - e0;
  const int ecount = deg + 1;                 // implicit self-loop at j==deg
  const float4 ad = *(const float4*)&a_dst4[(size_t)d*4];

  const int cg = (lane < 48)? lane : lane - 48;
  const int hg = (lane < 48)? (lane >> 4) : 0;
  const int cgo = cg*4;
  float4 acc = make_float4(0.f,0.f,0.f,0.f);
  float sl0=0.f, sl1=0.f, sl2=0.f;

  for (int base=0; base<ecount; base+=64){
    int j = base + lane;
    bool valid = j < ecount;
    int sn = d;
    if (j < deg) sn = col[e0+j];
    float4 as = *(const float4*)&a_src4[(size_t)sn*4];
    float l0 = as.x + ad.x; l0 = (l0>0.f)? l0 : 0.2f*l0;
    float l1 = as.y + ad.y; l1 = (l1>0.f)? l1 : 0.2f*l1;
    float l2 = as.z + ad.z; l2 = (l2>0.f)? l2 : 0.2f*l2;
    float E0 = valid? __expf(l0) : 0.f;
    float E1 = valid? __expf(l1) : 0.f;
    float E2 = valid? __expf(l2) : 0.f;
    sl0 += E0; sl1 += E1; sl2 += E2;
    float4 st; st.x = E0; st.y = E1; st.z = E2; st.w = 0.f;
    *(float4*)&s_al[w][lane][0] = st;
    __builtin_amdgcn_wave_barrier();
    int cnt = ecount - base; if (cnt > 64) cnt = 64;
    int jj = 0;
    for (; jj+4 <= cnt; jj += 4){
      int sA = __builtin_amdgcn_readlane(sn, jj);
      int sB = __builtin_amdgcn_readlane(sn, jj+1);
      int sC = __builtin_amdgcn_readlane(sn, jj+2);
      int sD = __builtin_amdgcn_readlane(sn, jj+3);
      uint2 pA = *(const uint2*)(hb + sA*F + cgo);
      uint2 pB = *(const uint2*)(hb + sB*F + cgo);
      uint2 pC = *(const uint2*)(hb + sC*F + cgo);
      uint2 pD = *(const uint2*)(hb + sD*F + cgo);
      float aA = s_al[w][jj  ][hg];
      float aB = s_al[w][jj+1][hg];
      float aC = s_al[w][jj+2][hg];
      float aD = s_al[w][jj+3][hg];
      acc.x = fmaf(aA, __uint_as_float(pA.x << 16),         acc.x);
      acc.y = fmaf(aA, __uint_as_float(pA.x & 0xffff0000u), acc.y);
      acc.z = fmaf(aA, __uint_as_float(pA.y << 16),         acc.z);
      acc.w = fmaf(aA, __uint_as_float(pA.y & 0xffff0000u), acc.w);
      acc.x = fmaf(aB, __uint_as_float(pB.x << 16),         acc.x);
      acc.y = fmaf(aB, __uint_as_float(pB.x & 0xffff0000u), acc.y);
      acc.z = fmaf(aB, __uint_as_float(pB.y << 16),         acc.z);
      acc.w = fmaf(aB, __uint_as_float(pB.y & 0xffff0000u), acc.w);
      acc.x = fmaf(aC, __uint_as_float(pC.x << 16),         acc.x);
      acc.y = fmaf(aC, __uint_as_float(pC.x & 0xffff0000u), acc.y);
      acc.z = fmaf(aC, __uint_as_float(pC.y << 16),         acc.z);
      acc.w = fmaf(aC, __uint_as_float(pC.y & 0xffff0000u), acc.w);
      acc.x = fmaf(aD, __uint_as_float(pD.x << 16),         acc.x);
      acc.y = fmaf(aD, __uint_as_float(pD.x & 0xffff0000u), acc.y);
      acc.z = fmaf(aD, __uint_as_float(pD.y << 16),         acc.z);
      acc.w = fmaf(aD, __uint_as_float(pD.y & 0xffff0000u), acc.w);
    }
    for (; jj < cnt; jj++){
      int sA = __builtin_amdgcn_readlane(sn, jj);
      uint2 pA = *(const uint2*)(hb + sA*F + cgo);
      float aA = s_al[w][jj][hg];
      acc.x = fmaf(aA, __uint_as_float(pA.x << 16),         acc.x);
      acc.y = fmaf(aA, __uint_as_float(pA.x & 0xffff0000u), acc.y);
      acc.z = fmaf(aA, __uint_as_float(pA.y << 16),         acc.z);
      acc.w = fmaf(aA, __uint_as_float(pA.y & 0xffff0000u), acc.w);
    }
    __builtin_amdgcn_wave_barrier();
  }
  #pragma unroll
  for (int off=32; off; off>>=1){
    sl0 += __shfl_xor(sl0, off);
    sl1 += __shfl_xor(sl1, off);
    sl2 += __shfl_xor(sl2, off);
  }
  if (lane < 48){
    float inv = 1.f / ((hg==0)? sl0 : ((hg==1)? sl1 : sl2));
    float4 b4 = *(const float4*)&bias[cg*4];
    uint2 o;
    o.x = (u32)f2bf(fmaxf(fmaf(acc.x, inv, b4.x), 0.f))
        | ((u32)f2bf(fmaxf(fmaf(acc.y, inv, b4.y), 0.f)) << 16);
    o.y = (u32)f2bf(fmaxf(fmaf(acc.z, inv, b4.z), 0.f))
        | ((u32)f2bf(fmaxf(fmaf(acc.w, inv, b4.w), 0.f)) << 16);
    *(uint2*)&out[(size_t)d*F + cg*4] = o;
  }
}

// ---------------- output GEMM via MFMA, no LDS ----------------
__global__ __launch_bounds__(256) void gemm_out_mfma(const u16* __restrict__ A,
    const u16* __restrict__ Wt, const float* __restrict__ bias, float* __restrict__ out){
  const int t = threadIdx.x;
  const int wave = t >> 6, lane = t & 63;
  const int quad = lane >> 4, l16 = lane & 15;
  const int rbase = blockIdx.x*64 + wave*16;
  const int arow = rbase + l16;
  f32x4 acc[3];
  #pragma unroll
  for (int ct=0;ct<3;ct++) acc[ct] = (f32x4){0.f,0.f,0.f,0.f};
  #pragma unroll
  for (int ks=0; ks<6; ks++){
    const int k0 = ks*32;
    union { uint4 u; bf16x8 h; } cva;
    cva.u = make_uint4(0,0,0,0);
    if (arow < NN) cva.u = *(const uint4*)&A[(size_t)arow*F + k0 + quad*8];
    #pragma unroll
    for (int ct=0;ct<3;ct++){
      bf16x8 bfr = *(const bf16x8*)&Wt[(size_t)(ct*16 + l16)*F + k0 + quad*8];
      acc[ct] = __builtin_amdgcn_mfma_f32_16x16x32_bf16(cva.h, bfr, acc[ct], 0, 0, 0);
    }
  }
  #pragma unroll
  for (int ct=0;ct<3;ct++){
    const int n = ct*16 + l16;
    #pragma unroll
    for (int reg=0;reg<4;reg++){
      const int m = quad*4 + reg;
      const int grow = rbase + m;
      if (grow < NN && n < NC) out[(size_t)grow*NC + n] = acc[ct][reg] + bias[n];
    }
  }
}

extern "C" void kernel_launch(void* const* d_in, const int* in_sizes, int n_in,
                              void* d_out, int out_size, void* d_ws, size_t ws_size,
                              hipStream_t stream){
  const float* x    = (const float*)d_in[0];
  const int*   ei   = (const int*)  d_in[1];
  const float* W1   = (const float*)d_in[2];
  const float* as1  = (const float*)d_in[3];
  const float* ad1  = (const float*)d_in[4];
  const float* b1   = (const float*)d_in[5];
  const float* W2   = (const float*)d_in[6];
  const float* as2  = (const float*)d_in[7];
  const float* ad2  = (const float*)d_in[8];
  const float* b2   = (const float*)d_in[9];
  const float* Wout = (const float*)d_in[10];
  const float* bout = (const float*)d_in[11];
  float* out = (float*)d_out;

  // workspace carve-out
  u16* w1t = (u16*)d_ws;                          // F*KIN  (W1^T bf16)
  u16* w2t = w1t + (size_t)F*KIN;                 // F*F    (W2^T bf16)
  u16* wot = w2t + (size_t)F*F;                   // 48*F   (Wout^T bf16, padded)
  u16* hb1 = wot + (size_t)48*F;                  // NN*F
  u16* hb2 = hb1 + (size_t)NN*F;                  // NN*F
  u16* gb1 = hb2 + (size_t)NN*F;                  // NN*F
  u16* gb2 = gb1 + (size_t)NN*F;                  // NN*F
  float* a_src4 = (float*)(gb2 + (size_t)NN*F);   // NN*4
  float* a_dst4 = a_src4 + (size_t)NN*4;          // NN*4
  int* row_ptr  = (int*)(a_dst4 + (size_t)NN*4);  // NN+1
  int* col      = row_ptr + (NN+1);               // NE
  int* cnt      = col + NE;                       // NN

  const int* srcv = ei;
  const int* dstv = ei + NE;

  // CSR by destination (rebuilt every call):
  //   memset -> count+conv -> emit_all (partial+scan+emit fused) -> fill (inside gemm1)
  hipMemsetAsync(cnt, 0, NN*sizeof(int), stream);
  count_conv_kernel<<<CNT_BLKS + CONV_BLKS, 256, 0, stream>>>(dstv, cnt, W1, W2, Wout, w1t, w2t, wot);
  emit_all<<<EMIT_BLKS, 256, 0, stream>>>(cnt, row_ptr);

  const int AGG_GRID = (NN + 3)/4;
  // layer 1: GEMM (x converted inline) + piggybacked CSR fill blocks
  gemm_mfma<KIN,true,true><<<GEMM_GRID_C + CNT_BLKS, 256, 0, stream>>>(
      x, w1t, hb1, as1, ad1, a_src4, a_dst4, srcv, dstv, row_ptr, cnt, col);
  gat_agg_wave<<<AGG_GRID, 256, 0, stream>>>(hb1, a_src4, a_dst4, row_ptr, col, b1, gb1);
  // layer 2
  gemm_mfma<F,false,false><<<GEMM_GRID_C, 256, 0, stream>>>(
      gb1, w2t, hb2, as2, ad2, a_src4, a_dst4, nullptr, nullptr, nullptr, nullptr, nullptr);
  gat_agg_wave<<<AGG_GRID, 256, 0, stream>>>(hb2, a_src4, a_dst4, row_ptr, col, b2, gb2);
  // readout
  gemm_out_mfma<<<GEMM_GRID_C, 256, 0, stream>>>(gb2, wot, bout, out);
}